// Round 1
// baseline (2922.236 us; speedup 1.0000x reference)
//
#include <hip/hip_runtime.h>

// VectorQuantizer on MI355X (gfx950)
// x: [64,64,64,64] fp32 -> flat [N=262144, D=64]
// embeddings: [D=64, K=512] fp32 (codes are COLUMNS)
// out: quantized [N*D] fp32  ++  loss scalar (1 fp32)  => out_size = 16777217
//
// Strategy (round 1, correctness + fp32-VALU roofline):
//  - one thread per vector; x vector in 64 VGPRs
//  - k-loop tiled by 8; codebook reads are wave-uniform -> scalar loads
//  - dist score = ||e_k||^2 - 2 x.e_k  (||x||^2 constant per vector, dropped)
//  - near-tie safety: if (second - best) < 1e-3, redo exact fp64 argmin
//  - loss = 1.25 * mean((q-x)^2): shuffle reduce + 1 atomic per block
//  - ws is re-poisoned every launch -> prep kernel rebuilds cnorm/et/accum

#define NVEC 262144
#define DDIM 64
#define KCB  512

// ws layout (floats):
//   [0]           loss accumulator
//   [256 .. 767]  cnorm[k] = ||e_k||^2
//   [1024 .. ]    et[k][d] = embeddings[d][k]  (transposed codebook, 32768 floats)
#define WS_LOSS  0
#define WS_CNORM 256
#define WS_ET    1024

__global__ __launch_bounds__(512) void vq_prep(const float* __restrict__ emb,
                                               float* __restrict__ wsf) {
    int k = threadIdx.x;  // one thread per code, 512 threads
    float s = 0.f;
    float* et = wsf + WS_ET;
    #pragma unroll
    for (int d = 0; d < DDIM; ++d) {
        float e = emb[d * KCB + k];   // coalesced over k
        s += e * e;
        et[k * DDIM + d] = e;
    }
    wsf[WS_CNORM + k] = s;
    if (k == 0) wsf[WS_LOSS] = 0.f;
}

__global__ __launch_bounds__(256) void vq_main(const float* __restrict__ x,
                                               const float* __restrict__ emb,
                                               const float* __restrict__ wsf,
                                               float* __restrict__ out,
                                               float* __restrict__ loss_accum) {
    const int n = blockIdx.x * 256 + threadIdx.x;
    const float* __restrict__ cnorm = wsf + WS_CNORM;
    const float* __restrict__ et    = wsf + WS_ET;

    // ---- load x vector into registers (16 x float4) ----
    float xr[DDIM];
    {
        const float4* xp = (const float4*)(x + (size_t)n * DDIM);
        #pragma unroll
        for (int d4 = 0; d4 < DDIM / 4; ++d4) {
            float4 v = xp[d4];
            xr[4 * d4 + 0] = v.x; xr[4 * d4 + 1] = v.y;
            xr[4 * d4 + 2] = v.z; xr[4 * d4 + 3] = v.w;
        }
    }

    // ---- argmin over codes: score = ||e||^2 - 2 x.e ----
    float best = 3.4e38f, second = 3.4e38f;
    int bestk = 0;
    for (int k0 = 0; k0 < KCB; k0 += 8) {
        float acc[8];
        #pragma unroll
        for (int j = 0; j < 8; ++j) acc[j] = 0.f;
        #pragma unroll
        for (int d = 0; d < DDIM; ++d) {
            // wave-uniform address -> scalar loads, no VMEM/LDS pressure
            const float4* ep = (const float4*)(emb + d * KCB + k0);
            float4 e0 = ep[0];
            float4 e1 = ep[1];
            float xd = xr[d];
            acc[0] += xd * e0.x; acc[1] += xd * e0.y;
            acc[2] += xd * e0.z; acc[3] += xd * e0.w;
            acc[4] += xd * e1.x; acc[5] += xd * e1.y;
            acc[6] += xd * e1.z; acc[7] += xd * e1.w;
        }
        #pragma unroll
        for (int j = 0; j < 8; ++j) {
            float dist = cnorm[k0 + j] - 2.f * acc[j];
            if (dist < best) { second = best; best = dist; bestk = k0 + j; }
            else if (dist < second) { second = dist; }
        }
    }

    // ---- near-tie: exact fp64 argmin (true distance), earliest-k wins ----
    if (second - best < 1e-3f) {
        double bestd = 1e300;
        int bk = 0;
        for (int k = 0; k < KCB; ++k) {
            const float* ek = et + k * DDIM;  // wave-uniform
            double s = 0.0;
            #pragma unroll
            for (int d = 0; d < DDIM; ++d) {
                double diff = (double)xr[d] - (double)ek[d];
                s += diff * diff;
            }
            if (s < bestd) { bestd = s; bk = k; }
        }
        bestk = bk;
    }

    // ---- write quantized output + per-thread squared error ----
    float sq = 0.f;
    {
        const float4* qp = (const float4*)(et + bestk * DDIM);  // 16B gather, L1/L2-hot
        float4* op = (float4*)(out + (size_t)n * DDIM);
        #pragma unroll
        for (int d4 = 0; d4 < DDIM / 4; ++d4) {
            float4 q = qp[d4];
            op[d4] = q;
            float a = q.x - xr[4 * d4 + 0];
            float b = q.y - xr[4 * d4 + 1];
            float c = q.z - xr[4 * d4 + 2];
            float e = q.w - xr[4 * d4 + 3];
            sq += a * a + b * b + c * c + e * e;
        }
    }

    // ---- block reduction: wave shuffle (width 64) -> LDS -> 1 atomic ----
    #pragma unroll
    for (int off = 32; off > 0; off >>= 1)
        sq += __shfl_down(sq, off);
    __shared__ float red[4];
    const int lane = threadIdx.x & 63;
    const int wid  = threadIdx.x >> 6;
    if (lane == 0) red[wid] = sq;
    __syncthreads();
    if (threadIdx.x == 0) {
        float t = red[0] + red[1] + red[2] + red[3];
        atomicAdd(loss_accum, t);
    }
}

__global__ void vq_final(const float* __restrict__ loss_accum,
                         float* __restrict__ out) {
    // loss = beta*commit + codebook = 1.25 * mean((q-x)^2)
    out[(size_t)NVEC * DDIM] = 1.25f * loss_accum[0] / 16777216.f;
}

extern "C" void kernel_launch(void* const* d_in, const int* in_sizes, int n_in,
                              void* d_out, int out_size, void* d_ws, size_t ws_size,
                              hipStream_t stream) {
    const float* x   = (const float*)d_in[0];  // 16777216 fp32
    const float* emb = (const float*)d_in[1];  // 32768 fp32 = [64][512]
    float* out = (float*)d_out;                // 16777217 fp32
    float* wsf = (float*)d_ws;                 // needs ~132 KB

    vq_prep<<<1, 512, 0, stream>>>(emb, wsf);
    vq_main<<<NVEC / 256, 256, 0, stream>>>(x, emb, wsf, out, wsf + WS_LOSS);
    vq_final<<<1, 1, 0, stream>>>(wsf + WS_LOSS, out);
}

// Round 2
// 222.502 us; speedup vs baseline: 13.1335x; 13.1335x over previous
//
#include <hip/hip_runtime.h>

// VectorQuantizer on MI355X (gfx950) — round 2: bf16-split MFMA argmin
// x: [262144, 64] fp32; embeddings: [64, 512] fp32 (codes are COLUMNS)
// out: quantized [N*64] fp32 ++ loss scalar
//
// sim = x.e computed as xh.eh + xl.eh + xh.el (bf16 split, abs err ~3e-5)
// dist score = ||e||^2 - 2 sim  (||x||^2 dropped for argmin, re-added for loss)
// near-tie (gap < 1e-3): whole-wave cooperative exact fp64 rescan (rare)

#define NVEC 262144
#define DDIM 64
#define KCB  512
#define TIE_TH 1e-3f

// ws layout (4-byte units)
#define WS_LOSS  0
#define WS_CNORM 64                      // 512 floats
#define WS_ET    1024                    // 512*64 floats (code-major codebook)
#define WS_EH    (WS_ET + KCB * DDIM)    // 32 tiles * 2 chunks * 64 lanes * 16B
#define WS_EL    (WS_EH + 32 * 2 * 64 * 4)
#define WS_END   (WS_EL + 32 * 2 * 64 * 4)

typedef __attribute__((ext_vector_type(8))) short bf16x8;
typedef __attribute__((ext_vector_type(4))) float f32x4;

static __device__ __forceinline__ unsigned short f2bf_rne(float f) {
    unsigned u = __float_as_uint(f);
    unsigned r = (u + 0x7FFFu + ((u >> 16) & 1u)) >> 16;
    return (unsigned short)r;
}
static __device__ __forceinline__ float bf2f(unsigned short h) {
    return __uint_as_float(((unsigned)h) << 16);
}

// ---------------- prep 1: et (code-major fp32), cnorm, zero loss ----------------
__global__ __launch_bounds__(512) void vq_prep1(const float* __restrict__ emb,
                                                float* __restrict__ wsf) {
    int k = threadIdx.x;
    float s = 0.f;
    float* et = wsf + WS_ET;
    #pragma unroll
    for (int d = 0; d < DDIM; ++d) {
        float e = emb[d * KCB + k];
        s += e * e;
        et[k * DDIM + d] = e;
    }
    wsf[WS_CNORM + k] = s;
    if (k == 0) wsf[WS_LOSS] = 0.f;
}

// ---------------- prep 2: codebook MFMA A-fragments (hi/lo bf16) ----------------
// frag index ((t*2+c)*64 + lane): 8 bf16 = A[m = t*16+(lane&15)][k = c*32+quad*8+j]
__global__ __launch_bounds__(512) void vq_prep2(const float* __restrict__ emb,
                                                float* __restrict__ wsf) {
    int tid = blockIdx.x * 512 + threadIdx.x;   // 0..4095
    if (tid >= 32 * 2 * 64) return;
    int l = tid & 63;
    int c = (tid >> 6) & 1;
    int t = tid >> 7;
    int m = t * 16 + (l & 15);
    int dbase = c * 32 + ((l >> 4) & 3) * 8;
    unsigned hh[4], ll[4];
    #pragma unroll
    for (int j2 = 0; j2 < 4; ++j2) {
        float f0 = emb[(dbase + 2 * j2 + 0) * KCB + m];
        float f1 = emb[(dbase + 2 * j2 + 1) * KCB + m];
        unsigned short h0 = f2bf_rne(f0), h1 = f2bf_rne(f1);
        unsigned short l0 = f2bf_rne(f0 - bf2f(h0)), l1 = f2bf_rne(f1 - bf2f(h1));
        hh[j2] = (unsigned)h0 | ((unsigned)h1 << 16);
        ll[j2] = (unsigned)l0 | ((unsigned)l1 << 16);
    }
    uint4* ehp = (uint4*)(wsf + WS_EH);
    uint4* elp = (uint4*)(wsf + WS_EL);
    ehp[tid] = make_uint4(hh[0], hh[1], hh[2], hh[3]);
    elp[tid] = make_uint4(ll[0], ll[1], ll[2], ll[3]);
}

// ---------------- main: one wave handles 64 vectors vs all 512 codes ----------------
__global__ __launch_bounds__(256) void vq_main_mfma(const float* __restrict__ x,
                                                    const float* __restrict__ wsf,
                                                    float* __restrict__ out,
                                                    float* __restrict__ loss_accum) {
    const int lane = threadIdx.x & 63;
    const int quad = lane >> 4;
    const int nbase = (blockIdx.x * 4 + (threadIdx.x >> 6)) * 64;

    const float* __restrict__ cnorm = wsf + WS_CNORM;
    const float* __restrict__ et    = wsf + WS_ET;
    const bf16x8* __restrict__ ehp  = (const bf16x8*)(wsf + WS_EH);
    const bf16x8* __restrict__ elp  = (const bf16x8*)(wsf + WS_EL);

    // ---- load x tile, build B-fragments (hi/lo), accumulate ||x||^2 ----
    bf16x8 xh[4][2], xl[4][2];
    float xnorm[4];
    #pragma unroll
    for (int j = 0; j < 4; ++j) {
        float s = 0.f;
        #pragma unroll
        for (int c = 0; c < 2; ++c) {
            const float* xrow = x + (size_t)(nbase + j * 16 + (lane & 15)) * DDIM
                                  + c * 32 + quad * 8;
            float4 xa = *(const float4*)xrow;
            float4 xb = *(const float4*)(xrow + 4);
            s += xa.x * xa.x + xa.y * xa.y + xa.z * xa.z + xa.w * xa.w;
            s += xb.x * xb.x + xb.y * xb.y + xb.z * xb.z + xb.w * xb.w;
            float f[8] = {xa.x, xa.y, xa.z, xa.w, xb.x, xb.y, xb.z, xb.w};
            union { bf16x8 v; unsigned short u[8]; } H, L;
            #pragma unroll
            for (int e = 0; e < 8; ++e) {
                unsigned short h = f2bf_rne(f[e]);
                H.u[e] = h;
                L.u[e] = f2bf_rne(f[e] - bf2f(h));
            }
            xh[j][c] = H.v;
            xl[j][c] = L.v;
        }
        // sum partial ||x||^2 across the 4 quads (bits 4,5 of lane)
        s += __shfl_xor(s, 16);
        s += __shfl_xor(s, 32);
        xnorm[j] = s;
    }

    // ---- argmin over 32 code-tiles ----
    float best[4], second[4];
    int bestv[4];  // t*16 + reg  (full code = bestv + quad*4)
    #pragma unroll
    for (int j = 0; j < 4; ++j) { best[j] = 3.4e38f; second[j] = 3.4e38f; bestv[j] = 0; }

    for (int t = 0; t < 32; ++t) {
        bf16x8 eh0 = ehp[(t * 2 + 0) * 64 + lane];
        bf16x8 eh1 = ehp[(t * 2 + 1) * 64 + lane];
        bf16x8 el0 = elp[(t * 2 + 0) * 64 + lane];
        bf16x8 el1 = elp[(t * 2 + 1) * 64 + lane];
        float4 cn = *(const float4*)(cnorm + t * 16 + quad * 4);
        const int kb = t * 16;
        #pragma unroll
        for (int j = 0; j < 4; ++j) {
            f32x4 acc = {0.f, 0.f, 0.f, 0.f};
            acc = __builtin_amdgcn_mfma_f32_16x16x32_bf16(eh0, xh[j][0], acc, 0, 0, 0);
            acc = __builtin_amdgcn_mfma_f32_16x16x32_bf16(eh1, xh[j][1], acc, 0, 0, 0);
            acc = __builtin_amdgcn_mfma_f32_16x16x32_bf16(el0, xh[j][0], acc, 0, 0, 0);
            acc = __builtin_amdgcn_mfma_f32_16x16x32_bf16(el1, xh[j][1], acc, 0, 0, 0);
            acc = __builtin_amdgcn_mfma_f32_16x16x32_bf16(eh0, xl[j][0], acc, 0, 0, 0);
            acc = __builtin_amdgcn_mfma_f32_16x16x32_bf16(eh1, xl[j][1], acc, 0, 0, 0);
            float cns[4] = {cn.x, cn.y, cn.z, cn.w};
            #pragma unroll
            for (int r = 0; r < 4; ++r) {
                float dist = __builtin_fmaf(-2.f, acc[r], cns[r]);
                bool lt = dist < best[j];
                second[j] = fminf(second[j], fmaxf(dist, best[j]));
                bestv[j] = lt ? (kb + r) : bestv[j];
                best[j] = fminf(best[j], dist);
            }
        }
    }

    // ---- reduce across the 4 quads (lanes n, n+16, n+32, n+48) ----
    int bk[4];
    #pragma unroll
    for (int j = 0; j < 4; ++j) bk[j] = bestv[j] + quad * 4;
    #pragma unroll
    for (int j = 0; j < 4; ++j) {
        #pragma unroll
        for (int m = 16; m <= 32; m <<= 1) {
            float ob = __shfl_xor(best[j], m);
            float os = __shfl_xor(second[j], m);
            int   ok = __shfl_xor(bk[j], m);
            float nb = fminf(best[j], ob);
            float ns = fminf(fminf(second[j], os), fmaxf(best[j], ob));
            bool take = (ob < best[j]) || (ob == best[j] && ok < bk[j]);
            bk[j] = take ? ok : bk[j];
            best[j] = nb;
            second[j] = ns;
        }
    }

    // ---- near-tie: whole-wave cooperative exact fp64 rescan (rare) ----
    #pragma unroll
    for (int j = 0; j < 4; ++j) {
        unsigned long long need = __ballot(second[j] - best[j] < TIE_TH) & 0xFFFFULL;
        while (need) {
            int nl = __ffsll(need) - 1;
            need &= need - 1;
            const float* xr = x + (size_t)(nbase + j * 16 + nl) * DDIM;
            double dmin = 1e300;
            int kmin = 0;
            #pragma unroll
            for (int i = 0; i < 8; ++i) {
                int k = lane * 8 + i;
                const float* er = et + k * DDIM;
                double s = 0.0;
                for (int d4 = 0; d4 < 16; ++d4) {
                    float4 xv = *(const float4*)(xr + d4 * 4);
                    float4 ev = *(const float4*)(er + d4 * 4);
                    double a = (double)xv.x - (double)ev.x; s += a * a;
                    double b = (double)xv.y - (double)ev.y; s += b * b;
                    double c = (double)xv.z - (double)ev.z; s += c * c;
                    double e = (double)xv.w - (double)ev.w; s += e * e;
                }
                if (s < dmin) { dmin = s; kmin = k; }
            }
            #pragma unroll
            for (int m = 1; m < 64; m <<= 1) {
                double od = __shfl_xor(dmin, m);
                int   ok = __shfl_xor(kmin, m);
                if (od < dmin || (od == dmin && ok < kmin)) { dmin = od; kmin = ok; }
            }
            if ((lane & 15) == nl) {
                bk[j] = kmin;
                best[j] = (float)dmin - xnorm[j];  // keep loss exact
            }
        }
    }

    // ---- loss partial: sum (q-x)^2 = xnorm + best over this wave's 64 n ----
    float ls = 0.f;
    if (lane < 16) {
        #pragma unroll
        for (int j = 0; j < 4; ++j) ls += fmaxf(xnorm[j] + best[j], 0.f);
    }
    #pragma unroll
    for (int m = 1; m < 64; m <<= 1) ls += __shfl_xor(ls, m);
    if (lane == 0) atomicAdd(loss_accum, ls);

    // ---- write quantized rows: lane -> (n = lane>>2, 64B slice = lane&3) ----
    #pragma unroll
    for (int j = 0; j < 4; ++j) {
        int bkn = __shfl(bk[j], lane >> 2);
        const float4* er = (const float4*)(et + (size_t)bkn * DDIM + (lane & 3) * 16);
        float4* op = (float4*)(out + (size_t)(nbase + j * 16 + (lane >> 2)) * DDIM
                                   + (lane & 3) * 16);
        op[0] = er[0]; op[1] = er[1]; op[2] = er[2]; op[3] = er[3];
    }
}

// ---------------- legacy fallback (round-1 kernel) if ws is too small ----------------
__global__ __launch_bounds__(256) void vq_main_legacy(const float* __restrict__ x,
                                                      const float* __restrict__ emb,
                                                      const float* __restrict__ wsf,
                                                      float* __restrict__ out,
                                                      float* __restrict__ loss_accum) {
    const int n = blockIdx.x * 256 + threadIdx.x;
    const float* __restrict__ cnorm = wsf + WS_CNORM;
    const float* __restrict__ et    = wsf + WS_ET;
    float xr[DDIM];
    {
        const float4* xp = (const float4*)(x + (size_t)n * DDIM);
        #pragma unroll
        for (int d4 = 0; d4 < DDIM / 4; ++d4) {
            float4 v = xp[d4];
            xr[4 * d4 + 0] = v.x; xr[4 * d4 + 1] = v.y;
            xr[4 * d4 + 2] = v.z; xr[4 * d4 + 3] = v.w;
        }
    }
    float best = 3.4e38f, second = 3.4e38f;
    int bestk = 0;
    for (int k0 = 0; k0 < KCB; k0 += 8) {
        float acc[8];
        #pragma unroll
        for (int j = 0; j < 8; ++j) acc[j] = 0.f;
        #pragma unroll
        for (int d = 0; d < DDIM; ++d) {
            const float4* ep = (const float4*)(et + (k0) * DDIM + d);  // dummy-ish
            (void)ep;
        }
        // recompute via et rows (code-major) for simplicity
        #pragma unroll
        for (int j = 0; j < 8; ++j) {
            const float* ek = et + (k0 + j) * DDIM;
            float s = 0.f;
            #pragma unroll
            for (int d = 0; d < DDIM; ++d) s += xr[d] * ek[d];
            acc[j] = s;
        }
        #pragma unroll
        for (int j = 0; j < 8; ++j) {
            float dist = cnorm[k0 + j] - 2.f * acc[j];
            if (dist < best) { second = best; best = dist; bestk = k0 + j; }
            else if (dist < second) { second = dist; }
        }
    }
    if (second - best < TIE_TH) {
        double bestd = 1e300;
        int bkk = 0;
        for (int k = 0; k < KCB; ++k) {
            const float* ek = et + k * DDIM;
            double s = 0.0;
            #pragma unroll
            for (int d = 0; d < DDIM; ++d) {
                double diff = (double)xr[d] - (double)ek[d];
                s += diff * diff;
            }
            if (s < bestd) { bestd = s; bkk = k; }
        }
        bestk = bkk;
    }
    float sq = 0.f;
    {
        const float4* qp = (const float4*)(et + bestk * DDIM);
        float4* op = (float4*)(out + (size_t)n * DDIM);
        #pragma unroll
        for (int d4 = 0; d4 < DDIM / 4; ++d4) {
            float4 q = qp[d4];
            op[d4] = q;
            float a = q.x - xr[4 * d4 + 0];
            float b = q.y - xr[4 * d4 + 1];
            float c = q.z - xr[4 * d4 + 2];
            float e = q.w - xr[4 * d4 + 3];
            sq += a * a + b * b + c * c + e * e;
        }
    }
    #pragma unroll
    for (int off = 32; off > 0; off >>= 1) sq += __shfl_down(sq, off);
    __shared__ float red[4];
    const int lane = threadIdx.x & 63;
    const int wid  = threadIdx.x >> 6;
    if (lane == 0) red[wid] = sq;
    __syncthreads();
    if (threadIdx.x == 0) atomicAdd(loss_accum, red[0] + red[1] + red[2] + red[3]);
}

__global__ void vq_final(const float* __restrict__ loss_accum,
                         float* __restrict__ out) {
    out[(size_t)NVEC * DDIM] = 1.25f * loss_accum[0] / 16777216.f;
}

extern "C" void kernel_launch(void* const* d_in, const int* in_sizes, int n_in,
                              void* d_out, int out_size, void* d_ws, size_t ws_size,
                              hipStream_t stream) {
    const float* x   = (const float*)d_in[0];
    const float* emb = (const float*)d_in[1];
    float* out = (float*)d_out;
    float* wsf = (float*)d_ws;

    vq_prep1<<<1, 512, 0, stream>>>(emb, wsf);
    if (ws_size >= (size_t)WS_END * 4) {
        vq_prep2<<<8, 512, 0, stream>>>(emb, wsf);
        vq_main_mfma<<<NVEC / 256, 256, 0, stream>>>(x, wsf, out, wsf + WS_LOSS);
    } else {
        vq_main_legacy<<<NVEC / 256, 256, 0, stream>>>(x, emb, wsf, out, wsf + WS_LOSS);
    }
    vq_final<<<1, 1, 0, stream>>>(wsf + WS_LOSS, out);
}